// Round 4
// baseline (366.896 us; speedup 1.0000x reference)
//
#include <hip/hip_runtime.h>
#include <hip/hip_bf16.h>
#include <math.h>

#define B 32
#define N 8400
#define M 60
#define C 80
#define KMAX 13
#define INF_COST 1e8f
#define WSLICE 2100   // N/4, one contiguous slice per wave

// ---------- shared math: MUST be bit-identical across kernels ----------
__device__ __forceinline__ float iou_fn(
    float px1, float py1, float px2, float py2,
    float gx1, float gy1, float gx2, float gy2)
{
#pragma clang fp contract(off)
    float ltx = fmaxf(px1, gx1), lty = fmaxf(py1, gy1);
    float rbx = fminf(px2, gx2), rby = fminf(py2, gy2);
    float wx = fmaxf(rbx - ltx, 0.0f), wy = fmaxf(rby - lty, 0.0f);
    float inter = wx * wy;
    float a1 = (px2 - px1) * (py2 - py1);
    float a2 = (gx2 - gx1) * (gy2 - gy1);
    float uni = fmaxf(a1 + a2 - inter, 1e-6f);
    return inter / uni;
}

__device__ __forceinline__ float cost_fn(
    float iou, float logit,
    float pcx, float pcy, float stride,
    float gcx, float gcy)
{
#pragma clang fp contract(off)
    float dx = pcx - gcx, dy = pcy - gcy;
    float dist = sqrtf(dx * dx + dy * dy) / stride;
    float soft = exp10f(dist - 3.0f);                 // can overflow to +inf (valid per ref)
    float iouc = -logf(iou + 1e-7f) * 3.0f;
    float sig = 1.0f / (1.0f + expf(-logit));
    float scale = iou - sig;
    float sc2 = scale * scale;
    float bce = fmaxf(logit, 0.0f) - logit * iou + log1pf(expf(-fabsf(logit)));
    float cls = bce * sc2;
    return (cls + iouc) + soft;
}

// ---------- kernel 1: valid_mask[b,n] ----------
__global__ __launch_bounds__(256) void k_valid(
    const float* __restrict__ priors,
    const float* __restrict__ gt_bboxes,
    const float* __restrict__ pad,
    unsigned char* __restrict__ valid)
{
    int idx = blockIdx.x * 256 + threadIdx.x;
    if (idx >= B * N) return;
    int b = idx / N, n = idx % N;
    float px = priors[n * 4 + 0];
    float py = priors[n * 4 + 1];
    const float* g = gt_bboxes + (size_t)b * M * 4;
    const float* pf = pad + (size_t)b * M;
    unsigned char v = 0;
    for (int m = 0; m < M; m++) {
        float x1 = g[m * 4 + 0], y1 = g[m * 4 + 1];
        float x2 = g[m * 4 + 2], y2 = g[m * 4 + 3];
        float mn = fminf(fminf(px - x1, py - y1), fminf(x2 - px, y2 - py));
        if (mn > 0.0f && pf[m] > 0.0f) { v = 1; break; }
    }
    valid[idx] = v;
}

// ---------- kernel 1b: per-m score columns, coalesced: t[b][m][n] = scores[b][n][lab[b][m]] ----------
__global__ __launch_bounds__(256) void k_transpose(
    const float* __restrict__ scores,
    const int*   __restrict__ labels,
    float* __restrict__ t)
{
    __shared__ float s_t[80][65];
    __shared__ int s_lab[M];

    const int i = blockIdx.x;
    const int cidx = (i & 7) * 528 + (i >> 3);
    const int b = cidx / 132;
    const int tile = cidx % 132;
    const int n0 = tile * 64;
    const int lim = (N - n0 < 64) ? (N - n0) : 64;

    if (threadIdx.x < M) s_lab[threadIdx.x] = labels[b * M + threadIdx.x];

    const float4* src4 = (const float4*)(scores + ((size_t)b * N + n0) * C);
    for (int idx = threadIdx.x; idx < lim * 20; idx += 256) {
        int r = idx / 20, q = idx % 20;
        float4 v = src4[r * 20 + q];
        s_t[4 * q + 0][r] = v.x;
        s_t[4 * q + 1][r] = v.y;
        s_t[4 * q + 2][r] = v.z;
        s_t[4 * q + 3][r] = v.w;
    }
    __syncthreads();

    for (int idx = threadIdx.x; idx < M * 16; idx += 256) {
        int m = idx >> 4, q = idx & 15;
        if (4 * q < lim) {
            int lab = s_lab[m];
            float4 v = make_float4(s_t[lab][4 * q + 0], s_t[lab][4 * q + 1],
                                   s_t[lab][4 * q + 2], s_t[lab][4 * q + 3]);
            *(float4*)(t + ((size_t)b * M + m) * N + n0 + 4 * q) = v;
        }
    }
}

// ---------- kernel 2: one block per (b,m); 4 waves pop independently; single merge ----------
__global__ __launch_bounds__(256) void k_select(
    const float* __restrict__ pred_bboxes,
    const float* __restrict__ pred_scores,
    const float* __restrict__ tsc,
    const float* __restrict__ priors,
    const int*   __restrict__ gt_labels,
    const float* __restrict__ gt_bboxes,
    const float* __restrict__ pad,
    const unsigned char* __restrict__ valid,
    float* __restrict__ cK, int* __restrict__ nK,
    int use_t)
{
    __shared__ float s_val[N];          // 33.6 KB
    __shared__ float s_tv[4][KMAX];     // per-wave top-13 iou (descending)
    __shared__ float s_bv[4][KMAX];     // per-wave bottom-13 cost (ascending lex)
    __shared__ int   s_bn[4][KMAX];

    const int i = blockIdx.x;
    const int bm = (i & 7) * 240 + (i >> 3);
    if (pad[bm] == 0.0f) return;        // padded GT column: cK/nK never consumed

    const int b = bm / M;
    const int tid = threadIdx.x;
    const int lane = tid & 63;
    const int w = tid >> 6;
    const int base = w * WSLICE;
    const int end = base + WSLICE;

    const float4 g = ((const float4*)gt_bboxes)[bm];
    const float gx1 = g.x, gy1 = g.y, gx2 = g.z, gy2 = g.w;
    const float4* pb4 = ((const float4*)pred_bboxes) + (size_t)b * N;

    // ---- phase 1: fill own slice with iou ----
    for (int n = base + lane; n < end; n += 64) {
        float4 p = pb4[n];
        s_val[n] = iou_fn(p.x, p.y, p.z, p.w, gx1, gy1, gx2, gy2);
    }
    __builtin_amdgcn_wave_barrier();

    // ---- 13 wave-local pops (no block barriers) ----
    for (int r = 0; r < KMAX; ++r) {
        float bv = -3.0f; int bi = 0x7fffffff;
        for (int n = base + lane; n < end; n += 64) {
            float v = s_val[n];
            if (v > bv) { bv = v; bi = n; }       // ascending n: first on tie
        }
#pragma unroll
        for (int d = 1; d < 64; d <<= 1) {
            float ov = __shfl_xor(bv, d);
            int   oi = __shfl_xor(bi, d);
            if (ov > bv || (ov == bv && oi < bi)) { bv = ov; bi = oi; }
        }
        if (lane == ((bi - base) & 63)) s_val[bi] = -2.0f;  // exclude (below any real iou)
        if (lane == 0) s_tv[w][r] = bv;
        __builtin_amdgcn_wave_barrier();
    }

    // ---- phase 2: fill own slice with cost ----
    const float gcx = (gx1 + gx2) * 0.5f, gcy = (gy1 + gy2) * 0.5f;
    const int label = gt_labels[bm];
    const float* tcol = tsc + (size_t)bm * N;
    const float* srow = pred_scores + (size_t)b * N * C;
    const unsigned char* vrow = valid + (size_t)b * N;
    const float4* pr4 = (const float4*)priors;

    for (int n = base + lane; n < end; n += 64) {
        float c;
        if (vrow[n]) {
            float4 p = pb4[n];
            float iou = iou_fn(p.x, p.y, p.z, p.w, gx1, gy1, gx2, gy2);
            float logit = use_t ? tcol[n] : srow[(size_t)n * C + label];
            float4 pr = pr4[n];
            c = cost_fn(iou, logit, pr.x, pr.y, pr.z, gcx, gcy);
        } else {
            c = INF_COST;
        }
        s_val[n] = c;
    }
    __builtin_amdgcn_wave_barrier();

    // ---- 13 wave-local pops: bottom (cost, n) lex ----
    for (int r = 0; r < KMAX; ++r) {
        float bv = INFINITY; int bi = 0x7fffffff;
        for (int n = base + lane; n < end; n += 64) {
            float v = s_val[n];
            // NaN markers fail both; real +inf beats sentinel by index
            if (v < bv || (v == bv && n < bi)) { bv = v; bi = n; }
        }
#pragma unroll
        for (int d = 1; d < 64; d <<= 1) {
            float ov = __shfl_xor(bv, d);
            int   oi = __shfl_xor(bi, d);
            if (ov < bv || (ov == bv && oi < bi)) { bv = ov; bi = oi; }
        }
        if (lane == ((bi - base) & 63)) s_val[bi] = __int_as_float(0x7fc00000); // NaN
        if (lane == 0) { s_bv[w][r] = bv; s_bn[w][r] = bi; }
        __builtin_amdgcn_wave_barrier();
    }

    __syncthreads();   // the ONLY block barrier

    if (tid == 0) {
        // merge descending top-13 across 4 waves; sum in descending order (== top_k().sum())
        int p0 = 0, p1 = 0, p2 = 0, p3 = 0;
        float ssum = 0.0f;
        for (int r = 0; r < KMAX; ++r) {
            float v0 = s_tv[0][p0], v1 = s_tv[1][p1], v2 = s_tv[2][p2], v3 = s_tv[3][p3];
            float bv = v0; int bw = 0;
            if (v1 > bv) { bv = v1; bw = 1; }
            if (v2 > bv) { bv = v2; bw = 2; }
            if (v3 > bv) { bv = v3; bw = 3; }
            ssum += bv;
            if (bw == 0) p0++; else if (bw == 1) p1++; else if (bw == 2) p2++; else p3++;
        }
        int K = (int)ssum;                    // trunc == astype(int32)
        if (K < 1) K = 1;

        // merge ascending (cost, n) lex; K-th element is the threshold pair
        int q0 = 0, q1 = 0, q2 = 0, q3 = 0;
        float ck = 0.0f; int nk = 0;
        for (int r = 0; r < K; ++r) {
            float bv = s_bv[0][q0]; int bn = s_bn[0][q0]; int bw = 0;
            float v; int nn;
            v = s_bv[1][q1]; nn = s_bn[1][q1];
            if (v < bv || (v == bv && nn < bn)) { bv = v; bn = nn; bw = 1; }
            v = s_bv[2][q2]; nn = s_bn[2][q2];
            if (v < bv || (v == bv && nn < bn)) { bv = v; bn = nn; bw = 2; }
            v = s_bv[3][q3]; nn = s_bn[3][q3];
            if (v < bv || (v == bv && nn < bn)) { bv = v; bn = nn; bw = 3; }
            ck = bv; nk = bn;
            if (bw == 0) q0++; else if (bw == 1) q1++; else if (bw == 2) q2++; else q3++;
        }
        cK[bm] = ck; nK[bm] = nk;
    }
}

// ---------- kernel 3: per-(b,n) row: matching + outputs ----------
__global__ __launch_bounds__(256) void k_assign(
    const float* __restrict__ pred_bboxes,
    const float* __restrict__ pred_scores,
    const float* __restrict__ tsc,
    const float* __restrict__ priors,
    const int*   __restrict__ gt_labels,
    const float* __restrict__ gt_bboxes,
    const float* __restrict__ pad,
    const unsigned char* __restrict__ valid,
    const float* __restrict__ cK,
    const int*   __restrict__ nK,
    float* __restrict__ out,
    int use_t)
{
    __shared__ float s_box[M][4];
    __shared__ float s_gc[M][2];
    __shared__ float s_ck[M];
    __shared__ int   s_lab[M];
    __shared__ int   s_nk[M];
    __shared__ unsigned char s_gtv[M];

    const int i = blockIdx.x;
    const int cidx = (i & 7) * 132 + (i >> 3);
    const int b = cidx / 33;
    const int chunk = cidx % 33;
    const int n = chunk * 256 + threadIdx.x;

    if (threadIdx.x < M) {
        int m = threadIdx.x, gi = b * M + m;
        float4 g = ((const float4*)gt_bboxes)[gi];
        s_box[m][0] = g.x; s_box[m][1] = g.y; s_box[m][2] = g.z; s_box[m][3] = g.w;
        s_gc[m][0] = (g.x + g.z) * 0.5f;
        s_gc[m][1] = (g.y + g.w) * 0.5f;
        s_ck[m] = cK[gi];
        s_lab[m] = gt_labels[gi];
        s_nk[m] = nK[gi];
        s_gtv[m] = (pad[gi] > 0.0f) ? 1 : 0;
    }
    __syncthreads();
    if (n >= N) return;

    const size_t idx = (size_t)b * N + n;
    const float4 p = ((const float4*)pred_bboxes)[idx];
    const float4 pr = ((const float4*)priors)[n];
    const int vn = valid[idx];
    const float* scores = pred_scores + idx * C;
    const float* tb = tsc + (size_t)b * M * N;

    int count = 0, firstm = -1;
    float firstiou = 0.0f;
    float minc = INFINITY; int amin = 0; float aminiou = 0.0f;

    for (int m = 0; m < M; m++) {
        float iou = iou_fn(p.x, p.y, p.z, p.w,
                           s_box[m][0], s_box[m][1], s_box[m][2], s_box[m][3]);
        float c;
        if (vn) {
            float logit = use_t ? tb[(size_t)m * N + n] : scores[s_lab[m]];
            c = cost_fn(iou, logit, pr.x, pr.y, pr.z, s_gc[m][0], s_gc[m][1]);
        } else {
            c = INF_COST;
        }

        if (c < minc) { minc = c; amin = m; aminiou = iou; }

        float ckm = s_ck[m]; int nkm = s_nk[m];
        bool matched = s_gtv[m] && (c < ckm || (c == ckm && n <= nkm));
        if (matched) { count++; if (firstm < 0) { firstm = m; firstiou = iou; } }
    }

    int mstar; float mi;
    if (count > 1)       { mstar = amin;   mi = aminiou; }
    else if (count == 1) { mstar = firstm; mi = firstiou; }
    else                 { mstar = -1;     mi = 0.0f; }

    float* o_lab = out;
    float* o_w   = out + (size_t)B * N;
    float* o_box = out + (size_t)2 * B * N;
    float* o_met = out + (size_t)6 * B * N;

    o_w[idx] = 1.0f;
    if (mstar >= 0) {
        o_lab[idx] = (float)s_lab[mstar];
        o_box[idx * 4 + 0] = s_box[mstar][0];
        o_box[idx * 4 + 1] = s_box[mstar][1];
        o_box[idx * 4 + 2] = s_box[mstar][2];
        o_box[idx * 4 + 3] = s_box[mstar][3];
        o_met[idx] = mi;
    } else {
        o_lab[idx] = (float)C;
        o_box[idx * 4 + 0] = 0.0f;
        o_box[idx * 4 + 1] = 0.0f;
        o_box[idx * 4 + 2] = 0.0f;
        o_box[idx * 4 + 3] = 0.0f;
        o_met[idx] = 0.0f;
    }
}

extern "C" void kernel_launch(void* const* d_in, const int* in_sizes, int n_in,
                              void* d_out, int out_size, void* d_ws, size_t ws_size,
                              hipStream_t stream) {
    const float* pred_bboxes = (const float*)d_in[0];
    const float* pred_scores = (const float*)d_in[1];
    const float* priors      = (const float*)d_in[2];
    const int*   gt_labels   = (const int*)d_in[3];
    const float* gt_bboxes   = (const float*)d_in[4];
    const float* pad         = (const float*)d_in[5];
    float* out = (float*)d_out;

    const size_t t_bytes = (size_t)B * M * N * sizeof(float);
    const size_t need = t_bytes + (size_t)B * N + (size_t)B * M * 8;
    const int use_t = (ws_size >= need) ? 1 : 0;

    unsigned char* ws = (unsigned char*)d_ws;
    float* tsc; unsigned char* valid; float* cKp; int* nKp;
    if (use_t) {
        tsc   = (float*)ws;
        valid = ws + t_bytes;
        cKp   = (float*)(ws + t_bytes + (size_t)B * N);
        nKp   = (int*)  (ws + t_bytes + (size_t)B * N + (size_t)B * M * 4);
    } else {
        tsc   = (float*)ws;
        valid = ws;
        cKp   = (float*)(ws + (size_t)B * N);
        nKp   = (int*)  (ws + (size_t)B * N + (size_t)B * M * 4);
    }

    k_valid<<<(B * N + 255) / 256, 256, 0, stream>>>(priors, gt_bboxes, pad, valid);
    if (use_t)
        k_transpose<<<B * 132, 256, 0, stream>>>(pred_scores, gt_labels, tsc);
    k_select<<<B * M, 256, 0, stream>>>(pred_bboxes, pred_scores, tsc, priors, gt_labels,
                                        gt_bboxes, pad, valid, cKp, nKp, use_t);
    k_assign<<<33 * B, 256, 0, stream>>>(pred_bboxes, pred_scores, tsc, priors, gt_labels,
                                         gt_bboxes, pad, valid, cKp, nKp, out, use_t);
}

// Round 5
// 331.424 us; speedup vs baseline: 1.1070x; 1.1070x over previous
//
#include <hip/hip_runtime.h>
#include <hip/hip_bf16.h>
#include <math.h>

#define B 32
#define N 8400
#define M 60
#define C 80
#define KMAX 13
#define INF_COST 1e8f
#define WSLICE 2100   // N/4, one contiguous slice per wave

// ---------- shared math: MUST be bit-identical across kernels ----------
__device__ __forceinline__ float iou_fn(
    float px1, float py1, float px2, float py2,
    float gx1, float gy1, float gx2, float gy2)
{
#pragma clang fp contract(off)
    float ltx = fmaxf(px1, gx1), lty = fmaxf(py1, gy1);
    float rbx = fminf(px2, gx2), rby = fminf(py2, gy2);
    float wx = fmaxf(rbx - ltx, 0.0f), wy = fmaxf(rby - lty, 0.0f);
    float inter = wx * wy;
    float a1 = (px2 - px1) * (py2 - py1);
    float a2 = (gx2 - gx1) * (gy2 - gy1);
    float uni = fmaxf(a1 + a2 - inter, 1e-6f);
    return inter / uni;
}

__device__ __forceinline__ float cost_fn(
    float iou, float logit,
    float pcx, float pcy, float stride,
    float gcx, float gcy)
{
#pragma clang fp contract(off)
    float dx = pcx - gcx, dy = pcy - gcy;
    float dist = sqrtf(dx * dx + dy * dy) / stride;
    float soft = exp10f(dist - 3.0f);                 // can overflow to +inf (valid per ref)
    float iouc = -logf(iou + 1e-7f) * 3.0f;
    float sig = 1.0f / (1.0f + expf(-logit));
    float scale = iou - sig;
    float sc2 = scale * scale;
    float bce = fmaxf(logit, 0.0f) - logit * iou + log1pf(expf(-fabsf(logit)));
    float cls = bce * sc2;
    return (cls + iouc) + soft;
}

// ---------- kernel 1: valid_mask[b,n] ----------
__global__ __launch_bounds__(256) void k_valid(
    const float* __restrict__ priors,
    const float* __restrict__ gt_bboxes,
    const float* __restrict__ pad,
    unsigned char* __restrict__ valid)
{
    int idx = blockIdx.x * 256 + threadIdx.x;
    if (idx >= B * N) return;
    int b = idx / N, n = idx % N;
    float px = priors[n * 4 + 0];
    float py = priors[n * 4 + 1];
    const float* g = gt_bboxes + (size_t)b * M * 4;
    const float* pf = pad + (size_t)b * M;
    unsigned char v = 0;
    for (int m = 0; m < M; m++) {
        float x1 = g[m * 4 + 0], y1 = g[m * 4 + 1];
        float x2 = g[m * 4 + 2], y2 = g[m * 4 + 3];
        float mn = fminf(fminf(px - x1, py - y1), fminf(x2 - px, y2 - py));
        if (mn > 0.0f && pf[m] > 0.0f) { v = 1; break; }
    }
    valid[idx] = v;
}

// ---------- kernel 1b: per-m score columns, coalesced: t[b][m][n] = scores[b][n][lab[b][m]] ----------
__global__ __launch_bounds__(256) void k_transpose(
    const float* __restrict__ scores,
    const int*   __restrict__ labels,
    float* __restrict__ t)
{
    __shared__ float s_t[80][65];
    __shared__ int s_lab[M];

    const int i = blockIdx.x;
    const int cidx = (i & 7) * 528 + (i >> 3);
    const int b = cidx / 132;
    const int tile = cidx % 132;
    const int n0 = tile * 64;
    const int lim = (N - n0 < 64) ? (N - n0) : 64;

    if (threadIdx.x < M) s_lab[threadIdx.x] = labels[b * M + threadIdx.x];

    const float4* src4 = (const float4*)(scores + ((size_t)b * N + n0) * C);
    for (int idx = threadIdx.x; idx < lim * 20; idx += 256) {
        int r = idx / 20, q = idx % 20;
        float4 v = src4[r * 20 + q];
        s_t[4 * q + 0][r] = v.x;
        s_t[4 * q + 1][r] = v.y;
        s_t[4 * q + 2][r] = v.z;
        s_t[4 * q + 3][r] = v.w;
    }
    __syncthreads();

    for (int idx = threadIdx.x; idx < M * 16; idx += 256) {
        int m = idx >> 4, q = idx & 15;
        if (4 * q < lim) {
            int lab = s_lab[m];
            float4 v = make_float4(s_t[lab][4 * q + 0], s_t[lab][4 * q + 1],
                                   s_t[lab][4 * q + 2], s_t[lab][4 * q + 3]);
            *(float4*)(t + ((size_t)b * M + m) * N + n0 + 4 * q) = v;
        }
    }
}

// ---------- kernel 2: single-pass register top-13 lists + butterfly pops; no big LDS ----------
__global__ __launch_bounds__(256) void k_select(
    const float* __restrict__ pred_bboxes,
    const float* __restrict__ pred_scores,
    const float* __restrict__ tsc,
    const float* __restrict__ priors,
    const int*   __restrict__ gt_labels,
    const float* __restrict__ gt_bboxes,
    const float* __restrict__ pad,
    const unsigned char* __restrict__ valid,
    float* __restrict__ cK, int* __restrict__ nK,
    int use_t)
{
    __shared__ float s_tv[4][KMAX];     // per-wave top-13 iou (descending)
    __shared__ float s_bv[4][KMAX];     // per-wave bottom-13 cost (ascending lex)
    __shared__ int   s_bn[4][KMAX];

    const int i = blockIdx.x;
    const int bm = (i & 7) * 240 + (i >> 3);
    if (pad[bm] == 0.0f) return;        // padded GT column: cK/nK never consumed

    const int b = bm / M;
    const int tid = threadIdx.x;
    const int lane = tid & 63;
    const int w = tid >> 6;
    const int base = w * WSLICE;
    const int end = base + WSLICE;

    const float4 g = ((const float4*)gt_bboxes)[bm];
    const float gx1 = g.x, gy1 = g.y, gx2 = g.z, gy2 = g.w;
    const float4* pb4 = ((const float4*)pred_bboxes) + (size_t)b * N;

    // ================= phase 1: per-lane top-13 iou (values only) =================
    float t13[KMAX];
#pragma unroll
    for (int j = 0; j < KMAX; ++j) t13[j] = -1.0f;

#pragma unroll 2
    for (int n = base + lane; n < end; n += 64) {
        float4 p = pb4[n];
        float v = iou_fn(p.x, p.y, p.z, p.w, gx1, gy1, gx2, gy2);
        // branchless descending insert (no-op when v <= t13[12])
#pragma unroll
        for (int j = KMAX - 1; j >= 1; --j)
            t13[j] = (t13[j] >= v) ? t13[j] : (t13[j - 1] >= v ? v : t13[j - 1]);
        t13[0] = (t13[0] >= v) ? t13[0] : v;
    }

    // 13 wave pops over list heads (max, tie -> lower lane; value sequence is unique)
    for (int r = 0; r < KMAX; ++r) {
        float bv = t13[0]; int bl = lane;
#pragma unroll
        for (int d = 1; d < 64; d <<= 1) {
            float ov = __shfl_xor(bv, d);
            int   ol = __shfl_xor(bl, d);
            if (ov > bv || (ov == bv && ol < bl)) { bv = ov; bl = ol; }
        }
        if (lane == 0) s_tv[w][r] = bv;
        if (lane == bl) {
#pragma unroll
            for (int j = 0; j < KMAX - 1; ++j) t13[j] = t13[j + 1];
            t13[KMAX - 1] = -1.0f;
        }
    }

    // ================= phase 2: per-lane bottom-13 (cost, n) lex =================
    const float gcx = (gx1 + gx2) * 0.5f, gcy = (gy1 + gy2) * 0.5f;
    const int label = gt_labels[bm];
    const float* tcol = tsc + (size_t)bm * N;
    const float* srow = pred_scores + (size_t)b * N * C;
    const unsigned char* vrow = valid + (size_t)b * N;
    const float4* pr4 = (const float4*)priors;

    float cv[KMAX]; int cn[KMAX];
#pragma unroll
    for (int j = 0; j < KMAX; ++j) { cv[j] = INFINITY; cn[j] = 0x7fffffff; }

#pragma unroll 2
    for (int n = base + lane; n < end; n += 64) {
        float c;
        if (vrow[n]) {
            float4 p = pb4[n];
            float iou = iou_fn(p.x, p.y, p.z, p.w, gx1, gy1, gx2, gy2);
            float logit = use_t ? tcol[n] : srow[(size_t)n * C + label];
            float4 pr = pr4[n];
            c = cost_fn(iou, logit, pr.x, pr.y, pr.z, gcx, gcy);
        } else {
            c = INF_COST;
        }
        // branchless ascending lex insert; existing equal-c entries (smaller n) stay ahead
        bool rej = (cv[KMAX - 1] < c) || (cv[KMAX - 1] == c && cn[KMAX - 1] < n);
        if (!rej) {
#pragma unroll
            for (int j = KMAX - 1; j >= 1; --j) {
                bool keep  = (cv[j] < c)     || (cv[j] == c     && cn[j] < n);
                bool pkeep = (cv[j - 1] < c) || (cv[j - 1] == c && cn[j - 1] < n);
                float nv = keep ? cv[j] : (pkeep ? c : cv[j - 1]);
                int   nn = keep ? cn[j] : (pkeep ? n : cn[j - 1]);
                cv[j] = nv; cn[j] = nn;
            }
            bool keep0 = (cv[0] < c) || (cv[0] == c && cn[0] < n);
            if (!keep0) { cv[0] = c; cn[0] = n; }
        }
    }

    // 13 wave pops: lex-min over heads; winner lane = (n - base) & 63
    for (int r = 0; r < KMAX; ++r) {
        float bv = cv[0]; int bn = cn[0];
#pragma unroll
        for (int d = 1; d < 64; d <<= 1) {
            float ov = __shfl_xor(bv, d);
            int   on = __shfl_xor(bn, d);
            if (ov < bv || (ov == bv && on < bn)) { bv = ov; bn = on; }
        }
        if (lane == 0) { s_bv[w][r] = bv; s_bn[w][r] = bn; }
        if (lane == ((bn - base) & 63)) {
#pragma unroll
            for (int j = 0; j < KMAX - 1; ++j) { cv[j] = cv[j + 1]; cn[j] = cn[j + 1]; }
            cv[KMAX - 1] = INFINITY; cn[KMAX - 1] = 0x7fffffff;
        }
    }

    __syncthreads();   // the ONLY block barrier

    if (tid == 0) {
        // merge descending top-13 across 4 waves; sum in descending order (== top_k().sum())
        int p0 = 0, p1 = 0, p2 = 0, p3 = 0;
        float ssum = 0.0f;
        for (int r = 0; r < KMAX; ++r) {
            float v0 = s_tv[0][p0], v1 = s_tv[1][p1], v2 = s_tv[2][p2], v3 = s_tv[3][p3];
            float bv = v0; int bw = 0;
            if (v1 > bv) { bv = v1; bw = 1; }
            if (v2 > bv) { bv = v2; bw = 2; }
            if (v3 > bv) { bv = v3; bw = 3; }
            ssum += bv;
            if (bw == 0) p0++; else if (bw == 1) p1++; else if (bw == 2) p2++; else p3++;
        }
        int K = (int)ssum;                    // trunc == astype(int32)
        if (K < 1) K = 1;

        // merge ascending (cost, n) lex; K-th element is the threshold pair
        int q0 = 0, q1 = 0, q2 = 0, q3 = 0;
        float ck = 0.0f; int nk = 0;
        for (int r = 0; r < K; ++r) {
            float bv = s_bv[0][q0]; int bn = s_bn[0][q0]; int bw = 0;
            float v; int nn;
            v = s_bv[1][q1]; nn = s_bn[1][q1];
            if (v < bv || (v == bv && nn < bn)) { bv = v; bn = nn; bw = 1; }
            v = s_bv[2][q2]; nn = s_bn[2][q2];
            if (v < bv || (v == bv && nn < bn)) { bv = v; bn = nn; bw = 2; }
            v = s_bv[3][q3]; nn = s_bn[3][q3];
            if (v < bv || (v == bv && nn < bn)) { bv = v; bn = nn; bw = 3; }
            ck = bv; nk = bn;
            if (bw == 0) q0++; else if (bw == 1) q1++; else if (bw == 2) q2++; else q3++;
        }
        cK[bm] = ck; nK[bm] = nk;
    }
}

// ---------- kernel 3: per-(b,n) row: matching + outputs ----------
__global__ __launch_bounds__(256) void k_assign(
    const float* __restrict__ pred_bboxes,
    const float* __restrict__ pred_scores,
    const float* __restrict__ tsc,
    const float* __restrict__ priors,
    const int*   __restrict__ gt_labels,
    const float* __restrict__ gt_bboxes,
    const float* __restrict__ pad,
    const unsigned char* __restrict__ valid,
    const float* __restrict__ cK,
    const int*   __restrict__ nK,
    float* __restrict__ out,
    int use_t)
{
    __shared__ float s_box[M][4];
    __shared__ float s_gc[M][2];
    __shared__ float s_ck[M];
    __shared__ int   s_lab[M];
    __shared__ int   s_nk[M];
    __shared__ unsigned char s_gtv[M];

    const int i = blockIdx.x;
    const int cidx = (i & 7) * 132 + (i >> 3);
    const int b = cidx / 33;
    const int chunk = cidx % 33;
    const int n = chunk * 256 + threadIdx.x;

    if (threadIdx.x < M) {
        int m = threadIdx.x, gi = b * M + m;
        float4 g = ((const float4*)gt_bboxes)[gi];
        s_box[m][0] = g.x; s_box[m][1] = g.y; s_box[m][2] = g.z; s_box[m][3] = g.w;
        s_gc[m][0] = (g.x + g.z) * 0.5f;
        s_gc[m][1] = (g.y + g.w) * 0.5f;
        s_ck[m] = cK[gi];
        s_lab[m] = gt_labels[gi];
        s_nk[m] = nK[gi];
        s_gtv[m] = (pad[gi] > 0.0f) ? 1 : 0;
    }
    __syncthreads();
    if (n >= N) return;

    const size_t idx = (size_t)b * N + n;
    const float4 p = ((const float4*)pred_bboxes)[idx];
    const float4 pr = ((const float4*)priors)[n];
    const int vn = valid[idx];
    const float* scores = pred_scores + idx * C;
    const float* tb = tsc + (size_t)b * M * N;

    int count = 0, firstm = -1;
    float firstiou = 0.0f;
    float minc = INFINITY; int amin = 0; float aminiou = 0.0f;

#pragma unroll 4
    for (int m = 0; m < M; m++) {
        float iou = iou_fn(p.x, p.y, p.z, p.w,
                           s_box[m][0], s_box[m][1], s_box[m][2], s_box[m][3]);
        float c;
        if (vn) {
            float logit = use_t ? tb[(size_t)m * N + n] : scores[s_lab[m]];
            c = cost_fn(iou, logit, pr.x, pr.y, pr.z, s_gc[m][0], s_gc[m][1]);
        } else {
            c = INF_COST;
        }

        if (c < minc) { minc = c; amin = m; aminiou = iou; }

        float ckm = s_ck[m]; int nkm = s_nk[m];
        bool matched = s_gtv[m] && (c < ckm || (c == ckm && n <= nkm));
        if (matched) { count++; if (firstm < 0) { firstm = m; firstiou = iou; } }
    }

    int mstar; float mi;
    if (count > 1)       { mstar = amin;   mi = aminiou; }
    else if (count == 1) { mstar = firstm; mi = firstiou; }
    else                 { mstar = -1;     mi = 0.0f; }

    float* o_lab = out;
    float* o_w   = out + (size_t)B * N;
    float* o_box = out + (size_t)2 * B * N;
    float* o_met = out + (size_t)6 * B * N;

    o_w[idx] = 1.0f;
    if (mstar >= 0) {
        o_lab[idx] = (float)s_lab[mstar];
        o_box[idx * 4 + 0] = s_box[mstar][0];
        o_box[idx * 4 + 1] = s_box[mstar][1];
        o_box[idx * 4 + 2] = s_box[mstar][2];
        o_box[idx * 4 + 3] = s_box[mstar][3];
        o_met[idx] = mi;
    } else {
        o_lab[idx] = (float)C;
        o_box[idx * 4 + 0] = 0.0f;
        o_box[idx * 4 + 1] = 0.0f;
        o_box[idx * 4 + 2] = 0.0f;
        o_box[idx * 4 + 3] = 0.0f;
        o_met[idx] = 0.0f;
    }
}

extern "C" void kernel_launch(void* const* d_in, const int* in_sizes, int n_in,
                              void* d_out, int out_size, void* d_ws, size_t ws_size,
                              hipStream_t stream) {
    const float* pred_bboxes = (const float*)d_in[0];
    const float* pred_scores = (const float*)d_in[1];
    const float* priors      = (const float*)d_in[2];
    const int*   gt_labels   = (const int*)d_in[3];
    const float* gt_bboxes   = (const float*)d_in[4];
    const float* pad         = (const float*)d_in[5];
    float* out = (float*)d_out;

    const size_t t_bytes = (size_t)B * M * N * sizeof(float);
    const size_t need = t_bytes + (size_t)B * N + (size_t)B * M * 8;
    const int use_t = (ws_size >= need) ? 1 : 0;

    unsigned char* ws = (unsigned char*)d_ws;
    float* tsc; unsigned char* valid; float* cKp; int* nKp;
    if (use_t) {
        tsc   = (float*)ws;
        valid = ws + t_bytes;
        cKp   = (float*)(ws + t_bytes + (size_t)B * N);
        nKp   = (int*)  (ws + t_bytes + (size_t)B * N + (size_t)B * M * 4);
    } else {
        tsc   = (float*)ws;
        valid = ws;
        cKp   = (float*)(ws + (size_t)B * N);
        nKp   = (int*)  (ws + (size_t)B * N + (size_t)B * M * 4);
    }

    k_valid<<<(B * N + 255) / 256, 256, 0, stream>>>(priors, gt_bboxes, pad, valid);
    if (use_t)
        k_transpose<<<B * 132, 256, 0, stream>>>(pred_scores, gt_labels, tsc);
    k_select<<<B * M, 256, 0, stream>>>(pred_bboxes, pred_scores, tsc, priors, gt_labels,
                                        gt_bboxes, pad, valid, cKp, nKp, use_t);
    k_assign<<<33 * B, 256, 0, stream>>>(pred_bboxes, pred_scores, tsc, priors, gt_labels,
                                         gt_bboxes, pad, valid, cKp, nKp, out, use_t);
}

// Round 6
// 330.803 us; speedup vs baseline: 1.1091x; 1.0019x over previous
//
#include <hip/hip_runtime.h>
#include <hip/hip_bf16.h>
#include <math.h>

#define B 32
#define N 8400
#define M 60
#define C 80
#define KMAX 13
#define INF_COST 1e8f
#define WSLICE 2100   // N/4, one contiguous slice per wave

// ---------- shared math: MUST be bit-identical across kernels ----------
__device__ __forceinline__ float iou_fn(
    float px1, float py1, float px2, float py2,
    float gx1, float gy1, float gx2, float gy2)
{
#pragma clang fp contract(off)
    float ltx = fmaxf(px1, gx1), lty = fmaxf(py1, gy1);
    float rbx = fminf(px2, gx2), rby = fminf(py2, gy2);
    float wx = fmaxf(rbx - ltx, 0.0f), wy = fmaxf(rby - lty, 0.0f);
    float inter = wx * wy;
    float a1 = (px2 - px1) * (py2 - py1);
    float a2 = (gx2 - gx1) * (gy2 - gy1);
    float uni = fmaxf(a1 + a2 - inter, 1e-6f);
    return inter / uni;
}

__device__ __forceinline__ float cost_fn(
    float iou, float logit,
    float pcx, float pcy, float stride,
    float gcx, float gcy)
{
#pragma clang fp contract(off)
    float dx = pcx - gcx, dy = pcy - gcy;
    float dist = sqrtf(dx * dx + dy * dy) / stride;
    float soft = exp10f(dist - 3.0f);                 // can overflow to +inf (valid per ref)
    float iouc = -logf(iou + 1e-7f) * 3.0f;
    float sig = 1.0f / (1.0f + expf(-logit));
    float scale = iou - sig;
    float sc2 = scale * scale;
    float bce = fmaxf(logit, 0.0f) - logit * iou + log1pf(expf(-fabsf(logit)));
    float cls = bce * sc2;
    return (cls + iouc) + soft;
}

// ---------- kernel 1: valid_mask[b,n] ----------
__global__ __launch_bounds__(256) void k_valid(
    const float* __restrict__ priors,
    const float* __restrict__ gt_bboxes,
    const float* __restrict__ pad,
    unsigned char* __restrict__ valid)
{
    int idx = blockIdx.x * 256 + threadIdx.x;
    if (idx >= B * N) return;
    int b = idx / N, n = idx % N;
    float px = priors[n * 4 + 0];
    float py = priors[n * 4 + 1];
    const float* g = gt_bboxes + (size_t)b * M * 4;
    const float* pf = pad + (size_t)b * M;
    unsigned char v = 0;
    for (int m = 0; m < M; m++) {
        float x1 = g[m * 4 + 0], y1 = g[m * 4 + 1];
        float x2 = g[m * 4 + 2], y2 = g[m * 4 + 3];
        float mn = fminf(fminf(px - x1, py - y1), fminf(x2 - px, y2 - py));
        if (mn > 0.0f && pf[m] > 0.0f) { v = 1; break; }
    }
    valid[idx] = v;
}

// ---------- kernel 1b: per-m score columns, coalesced: t[b][m][n] = scores[b][n][lab[b][m]] ----------
__global__ __launch_bounds__(256) void k_transpose(
    const float* __restrict__ scores,
    const int*   __restrict__ labels,
    float* __restrict__ t)
{
    __shared__ float s_t[80][65];
    __shared__ int s_lab[M];

    const int i = blockIdx.x;
    const int cidx = (i & 7) * 528 + (i >> 3);
    const int b = cidx / 132;
    const int tile = cidx % 132;
    const int n0 = tile * 64;
    const int lim = (N - n0 < 64) ? (N - n0) : 64;

    if (threadIdx.x < M) s_lab[threadIdx.x] = labels[b * M + threadIdx.x];

    const float4* src4 = (const float4*)(scores + ((size_t)b * N + n0) * C);
    for (int idx = threadIdx.x; idx < lim * 20; idx += 256) {
        int r = idx / 20, q = idx % 20;
        float4 v = src4[r * 20 + q];
        s_t[4 * q + 0][r] = v.x;
        s_t[4 * q + 1][r] = v.y;
        s_t[4 * q + 2][r] = v.z;
        s_t[4 * q + 3][r] = v.w;
    }
    __syncthreads();

    for (int idx = threadIdx.x; idx < M * 16; idx += 256) {
        int m = idx >> 4, q = idx & 15;
        if (4 * q < lim) {
            int lab = s_lab[m];
            float4 v = make_float4(s_t[lab][4 * q + 0], s_t[lab][4 * q + 1],
                                   s_t[lab][4 * q + 2], s_t[lab][4 * q + 3]);
            *(float4*)(t + ((size_t)b * M + m) * N + n0 + 4 * q) = v;
        }
    }
}

// ---------- kernel 2: single-pass register top-13 lists + butterfly pops; no big LDS ----------
__global__ __launch_bounds__(256) void k_select(
    const float* __restrict__ pred_bboxes,
    const float* __restrict__ pred_scores,
    const float* __restrict__ tsc,
    const float* __restrict__ priors,
    const int*   __restrict__ gt_labels,
    const float* __restrict__ gt_bboxes,
    const float* __restrict__ pad,
    const unsigned char* __restrict__ valid,
    float* __restrict__ cK, int* __restrict__ nK,
    int use_t)
{
    __shared__ float s_tv[4][KMAX];     // per-wave top-13 iou (descending)
    __shared__ float s_bv[4][KMAX];     // per-wave bottom-13 cost (ascending lex)
    __shared__ int   s_bn[4][KMAX];

    const int i = blockIdx.x;
    const int bm = (i & 7) * 240 + (i >> 3);
    if (pad[bm] == 0.0f) return;        // padded GT column: cK/nK never consumed

    const int b = bm / M;
    const int tid = threadIdx.x;
    const int lane = tid & 63;
    const int w = tid >> 6;
    const int base = w * WSLICE;
    const int end = base + WSLICE;

    const float4 g = ((const float4*)gt_bboxes)[bm];
    const float gx1 = g.x, gy1 = g.y, gx2 = g.z, gy2 = g.w;
    const float4* pb4 = ((const float4*)pred_bboxes) + (size_t)b * N;

    // ================= phase 1: per-lane top-13 iou (values only) =================
    float t13[KMAX];
#pragma unroll
    for (int j = 0; j < KMAX; ++j) t13[j] = -1.0f;

#pragma unroll 2
    for (int n = base + lane; n < end; n += 64) {
        float4 p = pb4[n];
        float v = iou_fn(p.x, p.y, p.z, p.w, gx1, gy1, gx2, gy2);
        // branchless descending insert (no-op when v <= t13[12])
#pragma unroll
        for (int j = KMAX - 1; j >= 1; --j)
            t13[j] = (t13[j] >= v) ? t13[j] : (t13[j - 1] >= v ? v : t13[j - 1]);
        t13[0] = (t13[0] >= v) ? t13[0] : v;
    }

    // 13 wave pops over list heads (max, tie -> lower lane; value sequence is unique)
    for (int r = 0; r < KMAX; ++r) {
        float bv = t13[0]; int bl = lane;
#pragma unroll
        for (int d = 1; d < 64; d <<= 1) {
            float ov = __shfl_xor(bv, d);
            int   ol = __shfl_xor(bl, d);
            if (ov > bv || (ov == bv && ol < bl)) { bv = ov; bl = ol; }
        }
        if (lane == 0) s_tv[w][r] = bv;
        if (lane == bl) {
#pragma unroll
            for (int j = 0; j < KMAX - 1; ++j) t13[j] = t13[j + 1];
            t13[KMAX - 1] = -1.0f;
        }
    }

    // ================= phase 2: per-lane bottom-13 (cost, n) lex =================
    const float gcx = (gx1 + gx2) * 0.5f, gcy = (gy1 + gy2) * 0.5f;
    const int label = gt_labels[bm];
    const float* tcol = tsc + (size_t)bm * N;
    const float* srow = pred_scores + (size_t)b * N * C;
    const unsigned char* vrow = valid + (size_t)b * N;
    const float4* pr4 = (const float4*)priors;

    float cv[KMAX]; int cn[KMAX];
#pragma unroll
    for (int j = 0; j < KMAX; ++j) { cv[j] = INFINITY; cn[j] = 0x7fffffff; }

#pragma unroll 2
    for (int n = base + lane; n < end; n += 64) {
        float c;
        if (vrow[n]) {
            float4 p = pb4[n];
            float iou = iou_fn(p.x, p.y, p.z, p.w, gx1, gy1, gx2, gy2);
            float logit = use_t ? tcol[n] : srow[(size_t)n * C + label];
            float4 pr = pr4[n];
            c = cost_fn(iou, logit, pr.x, pr.y, pr.z, gcx, gcy);
        } else {
            c = INF_COST;
        }
        // branchless ascending lex insert; existing equal-c entries (smaller n) stay ahead
        bool rej = (cv[KMAX - 1] < c) || (cv[KMAX - 1] == c && cn[KMAX - 1] < n);
        if (!rej) {
#pragma unroll
            for (int j = KMAX - 1; j >= 1; --j) {
                bool keep  = (cv[j] < c)     || (cv[j] == c     && cn[j] < n);
                bool pkeep = (cv[j - 1] < c) || (cv[j - 1] == c && cn[j - 1] < n);
                float nv = keep ? cv[j] : (pkeep ? c : cv[j - 1]);
                int   nn = keep ? cn[j] : (pkeep ? n : cn[j - 1]);
                cv[j] = nv; cn[j] = nn;
            }
            bool keep0 = (cv[0] < c) || (cv[0] == c && cn[0] < n);
            if (!keep0) { cv[0] = c; cn[0] = n; }
        }
    }

    // 13 wave pops: lex-min over heads; winner lane = (n - base) & 63
    for (int r = 0; r < KMAX; ++r) {
        float bv = cv[0]; int bn = cn[0];
#pragma unroll
        for (int d = 1; d < 64; d <<= 1) {
            float ov = __shfl_xor(bv, d);
            int   on = __shfl_xor(bn, d);
            if (ov < bv || (ov == bv && on < bn)) { bv = ov; bn = on; }
        }
        if (lane == 0) { s_bv[w][r] = bv; s_bn[w][r] = bn; }
        if (lane == ((bn - base) & 63)) {
#pragma unroll
            for (int j = 0; j < KMAX - 1; ++j) { cv[j] = cv[j + 1]; cn[j] = cn[j + 1]; }
            cv[KMAX - 1] = INFINITY; cn[KMAX - 1] = 0x7fffffff;
        }
    }

    __syncthreads();   // the ONLY block barrier

    if (tid == 0) {
        // merge descending top-13 across 4 waves; sum in descending order (== top_k().sum())
        int p0 = 0, p1 = 0, p2 = 0, p3 = 0;
        float ssum = 0.0f;
        for (int r = 0; r < KMAX; ++r) {
            float v0 = s_tv[0][p0], v1 = s_tv[1][p1], v2 = s_tv[2][p2], v3 = s_tv[3][p3];
            float bv = v0; int bw = 0;
            if (v1 > bv) { bv = v1; bw = 1; }
            if (v2 > bv) { bv = v2; bw = 2; }
            if (v3 > bv) { bv = v3; bw = 3; }
            ssum += bv;
            if (bw == 0) p0++; else if (bw == 1) p1++; else if (bw == 2) p2++; else p3++;
        }
        int K = (int)ssum;                    // trunc == astype(int32)
        if (K < 1) K = 1;

        // merge ascending (cost, n) lex; K-th element is the threshold pair
        int q0 = 0, q1 = 0, q2 = 0, q3 = 0;
        float ck = 0.0f; int nk = 0;
        for (int r = 0; r < K; ++r) {
            float bv = s_bv[0][q0]; int bn = s_bn[0][q0]; int bw = 0;
            float v; int nn;
            v = s_bv[1][q1]; nn = s_bn[1][q1];
            if (v < bv || (v == bv && nn < bn)) { bv = v; bn = nn; bw = 1; }
            v = s_bv[2][q2]; nn = s_bn[2][q2];
            if (v < bv || (v == bv && nn < bn)) { bv = v; bn = nn; bw = 2; }
            v = s_bv[3][q3]; nn = s_bn[3][q3];
            if (v < bv || (v == bv && nn < bn)) { bv = v; bn = nn; bw = 3; }
            ck = bv; nk = bn;
            if (bw == 0) q0++; else if (bw == 1) q1++; else if (bw == 2) q2++; else q3++;
        }
        cK[bm] = ck; nK[bm] = nk;
    }
}

// ---------- kernel 3: per-(b,n) row: matching + outputs ----------
__global__ __launch_bounds__(256) void k_assign(
    const float* __restrict__ pred_bboxes,
    const float* __restrict__ pred_scores,
    const float* __restrict__ tsc,
    const float* __restrict__ priors,
    const int*   __restrict__ gt_labels,
    const float* __restrict__ gt_bboxes,
    const float* __restrict__ pad,
    const unsigned char* __restrict__ valid,
    const float* __restrict__ cK,
    const int*   __restrict__ nK,
    float* __restrict__ out,
    int use_t)
{
    __shared__ float s_box[M][4];
    __shared__ float s_gc[M][2];
    __shared__ float s_ck[M];
    __shared__ int   s_lab[M];
    __shared__ int   s_nk[M];
    __shared__ unsigned char s_gtv[M];

    const int i = blockIdx.x;
    const int cidx = (i & 7) * 132 + (i >> 3);
    const int b = cidx / 33;
    const int chunk = cidx % 33;
    const int n = chunk * 256 + threadIdx.x;

    if (threadIdx.x < M) {
        int m = threadIdx.x, gi = b * M + m;
        float4 g = ((const float4*)gt_bboxes)[gi];
        s_box[m][0] = g.x; s_box[m][1] = g.y; s_box[m][2] = g.z; s_box[m][3] = g.w;
        s_gc[m][0] = (g.x + g.z) * 0.5f;
        s_gc[m][1] = (g.y + g.w) * 0.5f;
        s_ck[m] = cK[gi];
        s_lab[m] = gt_labels[gi];
        s_nk[m] = nK[gi];
        s_gtv[m] = (pad[gi] > 0.0f) ? 1 : 0;
    }
    __syncthreads();
    if (n >= N) return;

    const size_t idx = (size_t)b * N + n;
    const float4 p = ((const float4*)pred_bboxes)[idx];
    const float4 pr = ((const float4*)priors)[n];
    const int vn = valid[idx];
    const float* scores = pred_scores + idx * C;
    const float* tb = tsc + (size_t)b * M * N;

    int count = 0, firstm = -1;
    float firstiou = 0.0f;
    float minc = INFINITY; int amin = 0; float aminiou = 0.0f;

#pragma unroll 4
    for (int m = 0; m < M; m++) {
        float iou = iou_fn(p.x, p.y, p.z, p.w,
                           s_box[m][0], s_box[m][1], s_box[m][2], s_box[m][3]);
        float c;
        if (vn) {
            float logit = use_t ? tb[(size_t)m * N + n] : scores[s_lab[m]];
            c = cost_fn(iou, logit, pr.x, pr.y, pr.z, s_gc[m][0], s_gc[m][1]);
        } else {
            c = INF_COST;
        }

        if (c < minc) { minc = c; amin = m; aminiou = iou; }

        float ckm = s_ck[m]; int nkm = s_nk[m];
        bool matched = s_gtv[m] && (c < ckm || (c == ckm && n <= nkm));
        if (matched) { count++; if (firstm < 0) { firstm = m; firstiou = iou; } }
    }

    int mstar; float mi;
    if (count > 1)       { mstar = amin;   mi = aminiou; }
    else if (count == 1) { mstar = firstm; mi = firstiou; }
    else                 { mstar = -1;     mi = 0.0f; }

    float* o_lab = out;
    float* o_w   = out + (size_t)B * N;
    float* o_box = out + (size_t)2 * B * N;
    float* o_met = out + (size_t)6 * B * N;

    o_w[idx] = 1.0f;
    if (mstar >= 0) {
        o_lab[idx] = (float)s_lab[mstar];
        o_box[idx * 4 + 0] = s_box[mstar][0];
        o_box[idx * 4 + 1] = s_box[mstar][1];
        o_box[idx * 4 + 2] = s_box[mstar][2];
        o_box[idx * 4 + 3] = s_box[mstar][3];
        o_met[idx] = mi;
    } else {
        o_lab[idx] = (float)C;
        o_box[idx * 4 + 0] = 0.0f;
        o_box[idx * 4 + 1] = 0.0f;
        o_box[idx * 4 + 2] = 0.0f;
        o_box[idx * 4 + 3] = 0.0f;
        o_met[idx] = 0.0f;
    }
}

extern "C" void kernel_launch(void* const* d_in, const int* in_sizes, int n_in,
                              void* d_out, int out_size, void* d_ws, size_t ws_size,
                              hipStream_t stream) {
    const float* pred_bboxes = (const float*)d_in[0];
    const float* pred_scores = (const float*)d_in[1];
    const float* priors      = (const float*)d_in[2];
    const int*   gt_labels   = (const int*)d_in[3];
    const float* gt_bboxes   = (const float*)d_in[4];
    const float* pad         = (const float*)d_in[5];
    float* out = (float*)d_out;

    const size_t t_bytes = (size_t)B * M * N * sizeof(float);
    const size_t need = t_bytes + (size_t)B * N + (size_t)B * M * 8;
    const int use_t = (ws_size >= need) ? 1 : 0;

    unsigned char* ws = (unsigned char*)d_ws;
    float* tsc; unsigned char* valid; float* cKp; int* nKp;
    if (use_t) {
        tsc   = (float*)ws;
        valid = ws + t_bytes;
        cKp   = (float*)(ws + t_bytes + (size_t)B * N);
        nKp   = (int*)  (ws + t_bytes + (size_t)B * N + (size_t)B * M * 4);
    } else {
        tsc   = (float*)ws;
        valid = ws;
        cKp   = (float*)(ws + (size_t)B * N);
        nKp   = (int*)  (ws + (size_t)B * N + (size_t)B * M * 4);
    }

    k_valid<<<(B * N + 255) / 256, 256, 0, stream>>>(priors, gt_bboxes, pad, valid);
    if (use_t)
        k_transpose<<<B * 132, 256, 0, stream>>>(pred_scores, gt_labels, tsc);
    k_select<<<B * M, 256, 0, stream>>>(pred_bboxes, pred_scores, tsc, priors, gt_labels,
                                        gt_bboxes, pad, valid, cKp, nKp, use_t);
    k_assign<<<33 * B, 256, 0, stream>>>(pred_bboxes, pred_scores, tsc, priors, gt_labels,
                                         gt_bboxes, pad, valid, cKp, nKp, out, use_t);
}

// Round 7
// 289.919 us; speedup vs baseline: 1.2655x; 1.1410x over previous
//
#include <hip/hip_runtime.h>
#include <hip/hip_bf16.h>
#include <math.h>

#define B 32
#define N 8400
#define M 60
#define C 80
#define KMAX 13
#define INF_COST 1e8f
#define WSLICE 2100   // N/4, one contiguous slice per wave

// ---------- shared math: MUST be bit-identical across kernels ----------
__device__ __forceinline__ float iou_fn(
    float px1, float py1, float px2, float py2,
    float gx1, float gy1, float gx2, float gy2)
{
#pragma clang fp contract(off)
    float ltx = fmaxf(px1, gx1), lty = fmaxf(py1, gy1);
    float rbx = fminf(px2, gx2), rby = fminf(py2, gy2);
    float wx = fmaxf(rbx - ltx, 0.0f), wy = fmaxf(rby - lty, 0.0f);
    float inter = wx * wy;
    float a1 = (px2 - px1) * (py2 - py1);
    float a2 = (gx2 - gx1) * (gy2 - gy1);
    float uni = fmaxf(a1 + a2 - inter, 1e-6f);
    return inter / uni;
}

__device__ __forceinline__ float cost_fn(
    float iou, float logit,
    float pcx, float pcy, float stride,
    float gcx, float gcy)
{
#pragma clang fp contract(off)
    float dx = pcx - gcx, dy = pcy - gcy;
    float dist = sqrtf(dx * dx + dy * dy) / stride;
    float soft = exp10f(dist - 3.0f);                 // can overflow to +inf (valid per ref)
    float iouc = -logf(iou + 1e-7f) * 3.0f;
    float sig = 1.0f / (1.0f + expf(-logit));
    float scale = iou - sig;
    float sc2 = scale * scale;
    float bce = fmaxf(logit, 0.0f) - logit * iou + log1pf(expf(-fabsf(logit)));
    float cls = bce * sc2;
    return (cls + iouc) + soft;
}

// ---------- kernel 1: valid_mask[b,n] ----------
__global__ __launch_bounds__(256) void k_valid(
    const float* __restrict__ priors,
    const float* __restrict__ gt_bboxes,
    const float* __restrict__ pad,
    unsigned char* __restrict__ valid)
{
    int idx = blockIdx.x * 256 + threadIdx.x;
    if (idx >= B * N) return;
    int b = idx / N, n = idx % N;
    float px = priors[n * 4 + 0];
    float py = priors[n * 4 + 1];
    const float* g = gt_bboxes + (size_t)b * M * 4;
    const float* pf = pad + (size_t)b * M;
    unsigned char v = 0;
    for (int m = 0; m < M; m++) {
        float x1 = g[m * 4 + 0], y1 = g[m * 4 + 1];
        float x2 = g[m * 4 + 2], y2 = g[m * 4 + 3];
        float mn = fminf(fminf(px - x1, py - y1), fminf(x2 - px, y2 - py));
        if (mn > 0.0f && pf[m] > 0.0f) { v = 1; break; }
    }
    valid[idx] = v;
}

// ---------- kernel 1b: per-m score columns, coalesced: t[b][m][n] = scores[b][n][lab[b][m]] ----------
__global__ __launch_bounds__(256) void k_transpose(
    const float* __restrict__ scores,
    const int*   __restrict__ labels,
    float* __restrict__ t)
{
    __shared__ float s_t[80][65];
    __shared__ int s_lab[M];

    const int i = blockIdx.x;
    const int cidx = (i & 7) * 528 + (i >> 3);
    const int b = cidx / 132;
    const int tile = cidx % 132;
    const int n0 = tile * 64;
    const int lim = (N - n0 < 64) ? (N - n0) : 64;

    if (threadIdx.x < M) s_lab[threadIdx.x] = labels[b * M + threadIdx.x];

    const float4* src4 = (const float4*)(scores + ((size_t)b * N + n0) * C);
    for (int idx = threadIdx.x; idx < lim * 20; idx += 256) {
        int r = idx / 20, q = idx % 20;
        float4 v = src4[r * 20 + q];
        s_t[4 * q + 0][r] = v.x;
        s_t[4 * q + 1][r] = v.y;
        s_t[4 * q + 2][r] = v.z;
        s_t[4 * q + 3][r] = v.w;
    }
    __syncthreads();

    for (int idx = threadIdx.x; idx < M * 16; idx += 256) {
        int m = idx >> 4, q = idx & 15;
        if (4 * q < lim) {
            int lab = s_lab[m];
            float4 v = make_float4(s_t[lab][4 * q + 0], s_t[lab][4 * q + 1],
                                   s_t[lab][4 * q + 2], s_t[lab][4 * q + 3]);
            *(float4*)(t + ((size_t)b * M + m) * N + n0 + 4 * q) = v;
        }
    }
}

// ---------- kernel 2: fused single pass; writes cost matrix in-place over tsc ----------
__global__ __launch_bounds__(256) void k_select(
    const float* __restrict__ pred_bboxes,
    const float* __restrict__ pred_scores,
    float* __restrict__ tsc,                 // in: logit column; out: cost column
    const float* __restrict__ priors,
    const int*   __restrict__ gt_labels,
    const float* __restrict__ gt_bboxes,
    const float* __restrict__ pad,
    const unsigned char* __restrict__ valid,
    float* __restrict__ cK, int* __restrict__ nK,
    int use_t)
{
    __shared__ float s_tv[4][KMAX];     // per-wave top-13 iou (descending)
    __shared__ float s_bv[4][KMAX];     // per-wave bottom-13 cost (ascending lex)
    __shared__ int   s_bn[4][KMAX];

    const int i = blockIdx.x;
    const int bm = (i & 7) * 240 + (i >> 3);
    const bool do_lists = pad[bm] > 0.0f;   // padded column: cost-write only
    if (!do_lists && !use_t) return;

    const int b = bm / M;
    const int tid = threadIdx.x;
    const int lane = tid & 63;
    const int w = tid >> 6;
    const int base = w * WSLICE;
    const int end = base + WSLICE;

    const float4 g = ((const float4*)gt_bboxes)[bm];
    const float gx1 = g.x, gy1 = g.y, gx2 = g.z, gy2 = g.w;
    const float gcx = (gx1 + gx2) * 0.5f, gcy = (gy1 + gy2) * 0.5f;
    const int label = gt_labels[bm];
    const float4* pb4 = ((const float4*)pred_bboxes) + (size_t)b * N;
    float* tcol = tsc + (size_t)bm * N;
    const float* srow = pred_scores + (size_t)b * N * C;
    const unsigned char* vrow = valid + (size_t)b * N;
    const float4* pr4 = (const float4*)priors;

    float t13[KMAX];
    float cv[KMAX]; int cn[KMAX];
#pragma unroll
    for (int j = 0; j < KMAX; ++j) {
        t13[j] = -1.0f;
        cv[j] = INFINITY; cn[j] = 0x7fffffff;
    }

#pragma unroll 2
    for (int n = base + lane; n < end; n += 64) {
        float4 p = pb4[n];
        float v = iou_fn(p.x, p.y, p.z, p.w, gx1, gy1, gx2, gy2);

        if (do_lists && v > t13[KMAX - 1]) {   // equal-to-min insert is a no-op; skip it
#pragma unroll
            for (int j = KMAX - 1; j >= 1; --j)
                t13[j] = (t13[j] >= v) ? t13[j] : (t13[j - 1] >= v ? v : t13[j - 1]);
            t13[0] = (t13[0] >= v) ? t13[0] : v;
        }

        float c;
        if (vrow[n]) {
            float logit = use_t ? tcol[n] : srow[(size_t)n * C + label];
            float4 pr = pr4[n];
            c = cost_fn(v, logit, pr.x, pr.y, pr.z, gcx, gcy);
        } else {
            c = INF_COST;
        }
        if (use_t) tcol[n] = c;                // in-place: this lane owns [bm][n]

        if (do_lists) {
            bool rej = (cv[KMAX - 1] < c) || (cv[KMAX - 1] == c && cn[KMAX - 1] < n);
            if (!rej) {
#pragma unroll
                for (int j = KMAX - 1; j >= 1; --j) {
                    bool keep  = (cv[j] < c)     || (cv[j] == c     && cn[j] < n);
                    bool pkeep = (cv[j - 1] < c) || (cv[j - 1] == c && cn[j - 1] < n);
                    float nv = keep ? cv[j] : (pkeep ? c : cv[j - 1]);
                    int   nn = keep ? cn[j] : (pkeep ? n : cn[j - 1]);
                    cv[j] = nv; cn[j] = nn;
                }
                bool keep0 = (cv[0] < c) || (cv[0] == c && cn[0] < n);
                if (!keep0) { cv[0] = c; cn[0] = n; }
            }
        }
    }

    if (!do_lists) return;

    // ---- 13 wave pops over iou list heads (values only; ties value-identical) ----
    for (int r = 0; r < KMAX; ++r) {
        float bv = t13[0]; int bl = lane;
#pragma unroll
        for (int d = 1; d < 64; d <<= 1) {
            float ov = __shfl_xor(bv, d);
            int   ol = __shfl_xor(bl, d);
            if (ov > bv || (ov == bv && ol < bl)) { bv = ov; bl = ol; }
        }
        if (lane == 0) s_tv[w][r] = bv;
        if (lane == bl) {
#pragma unroll
            for (int j = 0; j < KMAX - 1; ++j) t13[j] = t13[j + 1];
            t13[KMAX - 1] = -1.0f;
        }
    }

    // ---- 13 wave pops: lex-min (cost, n); winner lane = (n - base) & 63 ----
    for (int r = 0; r < KMAX; ++r) {
        float bv = cv[0]; int bn = cn[0];
#pragma unroll
        for (int d = 1; d < 64; d <<= 1) {
            float ov = __shfl_xor(bv, d);
            int   on = __shfl_xor(bn, d);
            if (ov < bv || (ov == bv && on < bn)) { bv = ov; bn = on; }
        }
        if (lane == 0) { s_bv[w][r] = bv; s_bn[w][r] = bn; }
        if (lane == ((bn - base) & 63)) {
#pragma unroll
            for (int j = 0; j < KMAX - 1; ++j) { cv[j] = cv[j + 1]; cn[j] = cn[j + 1]; }
            cv[KMAX - 1] = INFINITY; cn[KMAX - 1] = 0x7fffffff;
        }
    }

    __syncthreads();   // the ONLY block barrier

    if (tid == 0) {
        // merge descending top-13 across 4 waves; sum in descending order (== top_k().sum())
        int p0 = 0, p1 = 0, p2 = 0, p3 = 0;
        float ssum = 0.0f;
        for (int r = 0; r < KMAX; ++r) {
            float v0 = s_tv[0][p0], v1 = s_tv[1][p1], v2 = s_tv[2][p2], v3 = s_tv[3][p3];
            float bv = v0; int bw = 0;
            if (v1 > bv) { bv = v1; bw = 1; }
            if (v2 > bv) { bv = v2; bw = 2; }
            if (v3 > bv) { bv = v3; bw = 3; }
            ssum += bv;
            if (bw == 0) p0++; else if (bw == 1) p1++; else if (bw == 2) p2++; else p3++;
        }
        int K = (int)ssum;                    // trunc == astype(int32)
        if (K < 1) K = 1;

        // merge ascending (cost, n) lex; K-th element is the threshold pair
        int q0 = 0, q1 = 0, q2 = 0, q3 = 0;
        float ck = 0.0f; int nk = 0;
        for (int r = 0; r < K; ++r) {
            float bv = s_bv[0][q0]; int bn = s_bn[0][q0]; int bw = 0;
            float v; int nn;
            v = s_bv[1][q1]; nn = s_bn[1][q1];
            if (v < bv || (v == bv && nn < bn)) { bv = v; bn = nn; bw = 1; }
            v = s_bv[2][q2]; nn = s_bn[2][q2];
            if (v < bv || (v == bv && nn < bn)) { bv = v; bn = nn; bw = 2; }
            v = s_bv[3][q3]; nn = s_bn[3][q3];
            if (v < bv || (v == bv && nn < bn)) { bv = v; bn = nn; bw = 3; }
            ck = bv; nk = bn;
            if (bw == 0) q0++; else if (bw == 1) q1++; else if (bw == 2) q2++; else q3++;
        }
        cK[bm] = ck; nK[bm] = nk;
    }
}

// ---------- kernel 3: per-(b,n) row; reads stored cost column (use_t) ----------
__global__ __launch_bounds__(256) void k_assign(
    const float* __restrict__ pred_bboxes,
    const float* __restrict__ pred_scores,
    const float* __restrict__ tsc,           // cost matrix after k_select (use_t)
    const float* __restrict__ priors,
    const int*   __restrict__ gt_labels,
    const float* __restrict__ gt_bboxes,
    const float* __restrict__ pad,
    const unsigned char* __restrict__ valid,
    const float* __restrict__ cK,
    const int*   __restrict__ nK,
    float* __restrict__ out,
    int use_t)
{
    __shared__ float s_box[M][4];
    __shared__ float s_gc[M][2];
    __shared__ float s_ck[M];
    __shared__ int   s_lab[M];
    __shared__ int   s_nk[M];
    __shared__ unsigned char s_gtv[M];

    const int i = blockIdx.x;
    const int cidx = (i & 7) * 132 + (i >> 3);
    const int b = cidx / 33;
    const int chunk = cidx % 33;
    const int n = chunk * 256 + threadIdx.x;

    if (threadIdx.x < M) {
        int m = threadIdx.x, gi = b * M + m;
        float4 g = ((const float4*)gt_bboxes)[gi];
        s_box[m][0] = g.x; s_box[m][1] = g.y; s_box[m][2] = g.z; s_box[m][3] = g.w;
        s_gc[m][0] = (g.x + g.z) * 0.5f;
        s_gc[m][1] = (g.y + g.w) * 0.5f;
        s_ck[m] = cK[gi];
        s_lab[m] = gt_labels[gi];
        s_nk[m] = nK[gi];
        s_gtv[m] = (pad[gi] > 0.0f) ? 1 : 0;
    }
    __syncthreads();
    if (n >= N) return;

    const size_t idx = (size_t)b * N + n;

    int count = 0, firstm = -1;
    float minc = INFINITY; int amin = 0;
    float firstiou = 0.0f, aminiou = 0.0f;

    if (use_t) {
        const float* tb = tsc + (size_t)b * M * N;
#pragma unroll 4
        for (int m = 0; m < M; m++) {
            float c = tb[(size_t)m * N + n];
            if (c < minc) { minc = c; amin = m; }
            float ckm = s_ck[m]; int nkm = s_nk[m];
            bool matched = s_gtv[m] && (c < ckm || (c == ckm && n <= nkm));
            if (matched) { count++; if (firstm < 0) firstm = m; }
        }
        int mstar = (count > 1) ? amin : firstm;     // count==0 -> firstm == -1
        float mi = 0.0f;
        if (mstar >= 0) {
            float4 p = ((const float4*)pred_bboxes)[idx];
            mi = iou_fn(p.x, p.y, p.z, p.w,
                        s_box[mstar][0], s_box[mstar][1], s_box[mstar][2], s_box[mstar][3]);
        }
        float* o_lab = out;
        float* o_w   = out + (size_t)B * N;
        float* o_box = out + (size_t)2 * B * N;
        float* o_met = out + (size_t)6 * B * N;
        o_w[idx] = 1.0f;
        if (mstar >= 0) {
            o_lab[idx] = (float)s_lab[mstar];
            o_box[idx * 4 + 0] = s_box[mstar][0];
            o_box[idx * 4 + 1] = s_box[mstar][1];
            o_box[idx * 4 + 2] = s_box[mstar][2];
            o_box[idx * 4 + 3] = s_box[mstar][3];
            o_met[idx] = mi;
        } else {
            o_lab[idx] = (float)C;
            o_box[idx * 4 + 0] = 0.0f;
            o_box[idx * 4 + 1] = 0.0f;
            o_box[idx * 4 + 2] = 0.0f;
            o_box[idx * 4 + 3] = 0.0f;
            o_met[idx] = 0.0f;
        }
        return;
    }

    // -------- fallback (use_t == 0): compute costs directly --------
    const float4 p = ((const float4*)pred_bboxes)[idx];
    const float4 pr = ((const float4*)priors)[n];
    const int vn = valid[idx];
    const float* scores = pred_scores + idx * C;

    for (int m = 0; m < M; m++) {
        float iou = iou_fn(p.x, p.y, p.z, p.w,
                           s_box[m][0], s_box[m][1], s_box[m][2], s_box[m][3]);
        float c;
        if (vn) {
            float logit = scores[s_lab[m]];
            c = cost_fn(iou, logit, pr.x, pr.y, pr.z, s_gc[m][0], s_gc[m][1]);
        } else {
            c = INF_COST;
        }
        if (c < minc) { minc = c; amin = m; aminiou = iou; }
        float ckm = s_ck[m]; int nkm = s_nk[m];
        bool matched = s_gtv[m] && (c < ckm || (c == ckm && n <= nkm));
        if (matched) { count++; if (firstm < 0) { firstm = m; firstiou = iou; } }
    }

    int mstar; float mi;
    if (count > 1)       { mstar = amin;   mi = aminiou; }
    else if (count == 1) { mstar = firstm; mi = firstiou; }
    else                 { mstar = -1;     mi = 0.0f; }

    float* o_lab = out;
    float* o_w   = out + (size_t)B * N;
    float* o_box = out + (size_t)2 * B * N;
    float* o_met = out + (size_t)6 * B * N;
    o_w[idx] = 1.0f;
    if (mstar >= 0) {
        o_lab[idx] = (float)s_lab[mstar];
        o_box[idx * 4 + 0] = s_box[mstar][0];
        o_box[idx * 4 + 1] = s_box[mstar][1];
        o_box[idx * 4 + 2] = s_box[mstar][2];
        o_box[idx * 4 + 3] = s_box[mstar][3];
        o_met[idx] = mi;
    } else {
        o_lab[idx] = (float)C;
        o_box[idx * 4 + 0] = 0.0f;
        o_box[idx * 4 + 1] = 0.0f;
        o_box[idx * 4 + 2] = 0.0f;
        o_box[idx * 4 + 3] = 0.0f;
        o_met[idx] = 0.0f;
    }
}

extern "C" void kernel_launch(void* const* d_in, const int* in_sizes, int n_in,
                              void* d_out, int out_size, void* d_ws, size_t ws_size,
                              hipStream_t stream) {
    const float* pred_bboxes = (const float*)d_in[0];
    const float* pred_scores = (const float*)d_in[1];
    const float* priors      = (const float*)d_in[2];
    const int*   gt_labels   = (const int*)d_in[3];
    const float* gt_bboxes   = (const float*)d_in[4];
    const float* pad         = (const float*)d_in[5];
    float* out = (float*)d_out;

    const size_t t_bytes = (size_t)B * M * N * sizeof(float);
    const size_t need = t_bytes + (size_t)B * N + (size_t)B * M * 8;
    const int use_t = (ws_size >= need) ? 1 : 0;

    unsigned char* ws = (unsigned char*)d_ws;
    float* tsc; unsigned char* valid; float* cKp; int* nKp;
    if (use_t) {
        tsc   = (float*)ws;
        valid = ws + t_bytes;
        cKp   = (float*)(ws + t_bytes + (size_t)B * N);
        nKp   = (int*)  (ws + t_bytes + (size_t)B * N + (size_t)B * M * 4);
    } else {
        tsc   = (float*)ws;   // never dereferenced
        valid = ws;
        cKp   = (float*)(ws + (size_t)B * N);
        nKp   = (int*)  (ws + (size_t)B * N + (size_t)B * M * 4);
    }

    k_valid<<<(B * N + 255) / 256, 256, 0, stream>>>(priors, gt_bboxes, pad, valid);
    if (use_t)
        k_transpose<<<B * 132, 256, 0, stream>>>(pred_scores, gt_labels, tsc);
    k_select<<<B * M, 256, 0, stream>>>(pred_bboxes, pred_scores, tsc, priors, gt_labels,
                                        gt_bboxes, pad, valid, cKp, nKp, use_t);
    k_assign<<<33 * B, 256, 0, stream>>>(pred_bboxes, pred_scores, tsc, priors, gt_labels,
                                         gt_bboxes, pad, valid, cKp, nKp, out, use_t);
}

// Round 8
// 231.721 us; speedup vs baseline: 1.5834x; 1.2512x over previous
//
#include <hip/hip_runtime.h>
#include <hip/hip_bf16.h>
#include <math.h>

#define B 32
#define N 8400
#define M 60
#define C 80
#define KMAX 13
#define INF_COST 1e8f

// ---------- shared math: MUST be bit-identical across kernels ----------
__device__ __forceinline__ float iou_fn(
    float px1, float py1, float px2, float py2,
    float gx1, float gy1, float gx2, float gy2)
{
#pragma clang fp contract(off)
    float ltx = fmaxf(px1, gx1), lty = fmaxf(py1, gy1);
    float rbx = fminf(px2, gx2), rby = fminf(py2, gy2);
    float wx = fmaxf(rbx - ltx, 0.0f), wy = fmaxf(rby - lty, 0.0f);
    float inter = wx * wy;
    float a1 = (px2 - px1) * (py2 - py1);
    float a2 = (gx2 - gx1) * (gy2 - gy1);
    float uni = fmaxf(a1 + a2 - inter, 1e-6f);
    return inter / uni;
}

__device__ __forceinline__ float cost_fn(
    float iou, float logit,
    float pcx, float pcy, float stride,
    float gcx, float gcy)
{
#pragma clang fp contract(off)
    float dx = pcx - gcx, dy = pcy - gcy;
    float dist = sqrtf(dx * dx + dy * dy) / stride;
    float soft = exp10f(dist - 3.0f);                 // can overflow to +inf (valid per ref)
    float iouc = -logf(iou + 1e-7f) * 3.0f;
    float sig = 1.0f / (1.0f + expf(-logit));
    float scale = iou - sig;
    float sc2 = scale * scale;
    float bce = fmaxf(logit, 0.0f) - logit * iou + log1pf(expf(-fabsf(logit)));
    float cls = bce * sc2;
    return (cls + iouc) + soft;
}

// ---------- kernel 1: valid_mask[b,n] ----------
__global__ __launch_bounds__(256) void k_valid(
    const float* __restrict__ priors,
    const float* __restrict__ gt_bboxes,
    const float* __restrict__ pad,
    unsigned char* __restrict__ valid)
{
    int idx = blockIdx.x * 256 + threadIdx.x;
    if (idx >= B * N) return;
    int b = idx / N, n = idx % N;
    float px = priors[n * 4 + 0];
    float py = priors[n * 4 + 1];
    const float* g = gt_bboxes + (size_t)b * M * 4;
    const float* pf = pad + (size_t)b * M;
    unsigned char v = 0;
    for (int m = 0; m < M; m++) {
        float x1 = g[m * 4 + 0], y1 = g[m * 4 + 1];
        float x2 = g[m * 4 + 2], y2 = g[m * 4 + 3];
        float mn = fminf(fminf(px - x1, py - y1), fminf(x2 - px, y2 - py));
        if (mn > 0.0f && pf[m] > 0.0f) { v = 1; break; }
    }
    valid[idx] = v;
}

// ---------- kernel 1b: per-m score columns, coalesced: t[b][m][n] = scores[b][n][lab[b][m]] ----------
__global__ __launch_bounds__(256) void k_transpose(
    const float* __restrict__ scores,
    const int*   __restrict__ labels,
    float* __restrict__ t)
{
    __shared__ float s_t[80][65];
    __shared__ int s_lab[M];

    const int i = blockIdx.x;
    const int cidx = (i & 7) * 528 + (i >> 3);
    const int b = cidx / 132;
    const int tile = cidx % 132;
    const int n0 = tile * 64;
    const int lim = (N - n0 < 64) ? (N - n0) : 64;

    if (threadIdx.x < M) s_lab[threadIdx.x] = labels[b * M + threadIdx.x];

    const float4* src4 = (const float4*)(scores + ((size_t)b * N + n0) * C);
    for (int idx = threadIdx.x; idx < lim * 20; idx += 256) {
        int r = idx / 20, q = idx % 20;
        float4 v = src4[r * 20 + q];
        s_t[4 * q + 0][r] = v.x;
        s_t[4 * q + 1][r] = v.y;
        s_t[4 * q + 2][r] = v.z;
        s_t[4 * q + 3][r] = v.w;
    }
    __syncthreads();

    for (int idx = threadIdx.x; idx < M * 16; idx += 256) {
        int m = idx >> 4, q = idx & 15;
        if (4 * q < lim) {
            int lab = s_lab[m];
            float4 v = make_float4(s_t[lab][4 * q + 0], s_t[lab][4 * q + 1],
                                   s_t[lab][4 * q + 2], s_t[lab][4 * q + 3]);
            *(float4*)(t + ((size_t)b * M + m) * N + n0 + 4 * q) = v;
        }
    }
}

// ---------- radix-select helpers (block of 256, hist = 4 copies x 256 bins) ----------
__device__ __forceinline__ void hist_zero(unsigned (*s_h)[256], int tid) {
    unsigned* f = &s_h[0][0];
    for (int j = tid; j < 1024; j += 256) f[j] = 0;
}

// prefix over 256 bins; writes: s_sel[2]=total; if need!=0: s_sel[0]=bin, s_sel[1]=#items in bins<bin
__device__ __forceinline__ void hist_pick(unsigned (*s_h)[256], unsigned* s_wsum,
    unsigned* s_sel, int tid, int lane, int w, unsigned need)
{
    unsigned cnt = s_h[0][tid] + s_h[1][tid] + s_h[2][tid] + s_h[3][tid];
    unsigned x = cnt;
#pragma unroll
    for (int d = 1; d < 64; d <<= 1) {
        unsigned y = (unsigned)__shfl_up((int)x, d);
        if (lane >= d) x += y;
    }
    if (lane == 63) s_wsum[w] = x;
    __syncthreads();
    unsigned off = 0;
    for (int ww = 0; ww < w; ++ww) off += s_wsum[ww];
    unsigned incl = x + off;
    unsigned excl = incl - cnt;
    if (tid == 255) s_sel[2] = incl;
    if (need != 0u && excl < need && need <= incl) { s_sel[0] = (unsigned)tid; s_sel[1] = excl; }
    __syncthreads();
}

// ---------- kernel 2: radix-select per column; writes cost matrix in-place over tsc ----------
__global__ __launch_bounds__(256) void k_select(
    const float* __restrict__ pred_bboxes,
    const float* __restrict__ pred_scores,
    float* __restrict__ tsc,                 // in: logit column; out: cost column
    const float* __restrict__ priors,
    const int*   __restrict__ gt_labels,
    const float* __restrict__ gt_bboxes,
    const float* __restrict__ pad,
    const unsigned char* __restrict__ valid,
    float* __restrict__ cK, int* __restrict__ nK,
    int use_t)
{
    __shared__ float    s_val[N];        // 33.6 KB: iou, then cost
    __shared__ unsigned s_h[4][256];     // 4 KB histogram copies
    __shared__ unsigned s_wsum[4];
    __shared__ unsigned s_sel[4];
    __shared__ float    s_coll[16];
    __shared__ unsigned s_cnt;

    const int i = blockIdx.x;
    const int bm = (i & 7) * 240 + (i >> 3);
    const bool do_lists = pad[bm] > 0.0f;
    if (!do_lists && !use_t) return;

    const int b = bm / M;
    const int tid = threadIdx.x;
    const int lane = tid & 63;
    const int w = tid >> 6;

    const float4 g = ((const float4*)gt_bboxes)[bm];
    const float gx1 = g.x, gy1 = g.y, gx2 = g.z, gy2 = g.w;
    const float gcx = (gx1 + gx2) * 0.5f, gcy = (gy1 + gy2) * 0.5f;
    const int label = gt_labels[bm];
    const float4* pb4 = ((const float4*)pred_bboxes) + (size_t)b * N;
    float* tcol = tsc + (size_t)bm * N;
    const float* srow = pred_scores + (size_t)b * N * C;
    const unsigned char* vrow = valid + (size_t)b * N;
    const float4* pr4 = (const float4*)priors;

    if (!do_lists) {
        // padded GT column: cost write only (consumed by k_assign's argmin)
        for (int n = tid; n < N; n += 256) {
            float4 p = pb4[n];
            float iou = iou_fn(p.x, p.y, p.z, p.w, gx1, gy1, gx2, gy2);
            float c;
            if (vrow[n]) {
                float logit = tcol[n];
                float4 pr = pr4[n];
                c = cost_fn(iou, logit, pr.x, pr.y, pr.z, gcx, gcy);
            } else {
                c = INF_COST;
            }
            tcol[n] = c;
        }
        return;
    }

    // ======== pass A: iou -> LDS + fused level-0 histogram (positives only) ========
    hist_zero(s_h, tid);
    __syncthreads();
    for (int n = tid; n < N; n += 256) {
        float4 p = pb4[n];
        float v = iou_fn(p.x, p.y, p.z, p.w, gx1, gy1, gx2, gy2);
        s_val[n] = v;
        unsigned bits = __float_as_uint(v);            // positive floats: bits monotonic
        if (bits) atomicAdd(&s_h[tid & 3][bits >> 24], 1u);
    }
    __syncthreads();

    // ---- 13th-largest iou via 4-level radix descend; then desc-ordered sum ----
    hist_pick(s_h, s_wsum, s_sel, tid, lane, w, 0u);
    const unsigned total = s_sel[2];                   // # positive ious
    unsigned thr_i = 0;
    if (total >= 13u) {
        unsigned pref = 0, mask = 0, need = total - 12u;   // asc rank of 13th-largest
        for (int lev = 0; lev < 4; ++lev) {
            int shift = 24 - 8 * lev;
            if (lev) {
                hist_zero(s_h, tid);
                __syncthreads();
                for (int n = tid; n < N; n += 256) {
                    unsigned bits = __float_as_uint(s_val[n]);
                    if (bits && (bits & mask) == pref)
                        atomicAdd(&s_h[tid & 3][(bits >> shift) & 255u], 1u);
                }
                __syncthreads();
            }
            hist_pick(s_h, s_wsum, s_sel, tid, lane, w, need);
            pref |= s_sel[0] << shift;
            mask |= 0xFFu << shift;
            need -= s_sel[1];
        }
        thr_i = pref;                                  // exact 13th-largest value bits
    }
    if (tid == 0) s_cnt = 0;
    __syncthreads();
    for (int n = tid; n < N; n += 256) {
        unsigned bits = __float_as_uint(s_val[n]);
        if (bits > thr_i) {                            // >0 when thr_i==0 (total<13 case)
            unsigned p = atomicAdd(&s_cnt, 1u);
            if (p < 16u) s_coll[p] = s_val[n];         // guaranteed <= 12 items
        }
    }
    __syncthreads();
    if (tid == 0) {
        int cg = (int)s_cnt; if (cg > 13) cg = 13;
        for (int a = 1; a < cg; ++a) {                 // insertion sort desc (<=12 items)
            float key = s_coll[a]; int bp = a - 1;
            while (bp >= 0 && s_coll[bp] < key) { s_coll[bp + 1] = s_coll[bp]; --bp; }
            s_coll[bp + 1] = key;
        }
        float ss = 0.0f;
        for (int a = 0; a < cg; ++a) ss += s_coll[a];  // descending-order sum
        if (total >= 13u) {
            float thr = __uint_as_float(thr_i);
            for (int a = cg; a < 13; ++a) ss += thr;   // tied values, same order semantics
        }
        int K = (int)ss;                               // trunc == astype(int32)
        if (K < 1) K = 1;
        s_sel[3] = (unsigned)K;
    }
    __syncthreads();
    const unsigned K = s_sel[3];

    // ======== pass B: cost -> LDS (overwrite) + global + fused level-0 histogram ========
    hist_zero(s_h, tid);
    __syncthreads();
    for (int n = tid; n < N; n += 256) {
        float c;
        if (vrow[n]) {
            float iou = s_val[n];
            float logit = use_t ? tcol[n] : srow[(size_t)n * C + label];
            float4 pr = pr4[n];
            c = cost_fn(iou, logit, pr.x, pr.y, pr.z, gcx, gcy);
        } else {
            c = INF_COST;
        }
        if (use_t) tcol[n] = c;                        // same lane owns [bm][n]
        s_val[n] = c;                                  // cost always > 0: bits monotonic
        atomicAdd(&s_h[tid & 3][__float_as_uint(c) >> 24], 1u);
    }
    __syncthreads();

    // ---- K-th smallest cost value via radix descend ----
    unsigned pref = 0, mask = 0, need = K;
    for (int lev = 0; lev < 4; ++lev) {
        int shift = 24 - 8 * lev;
        if (lev) {
            hist_zero(s_h, tid);
            __syncthreads();
            for (int n = tid; n < N; n += 256) {
                unsigned bits = __float_as_uint(s_val[n]);
                if ((bits & mask) == pref)
                    atomicAdd(&s_h[tid & 3][(bits >> shift) & 255u], 1u);
            }
            __syncthreads();
        }
        hist_pick(s_h, s_wsum, s_sel, tid, lane, w, need);
        pref |= s_sel[0] << shift;
        mask |= 0xFFu << shift;
        need -= s_sel[1];
    }
    // need = 1-based rank among ties (ascending n): find that index
    {
        const int lo = tid * 33;
        const int hi = (lo + 33 < N) ? (lo + 33) : N;
        unsigned cnt = 0;
        for (int n = lo; n < hi; ++n) cnt += (__float_as_uint(s_val[n]) == pref) ? 1u : 0u;
        unsigned x = cnt;
#pragma unroll
        for (int d = 1; d < 64; d <<= 1) {
            unsigned y = (unsigned)__shfl_up((int)x, d);
            if (lane >= d) x += y;
        }
        if (lane == 63) s_wsum[w] = x;
        __syncthreads();
        unsigned off = 0;
        for (int ww = 0; ww < w; ++ww) off += s_wsum[ww];
        unsigned incl = x + off, excl = incl - cnt;
        if (excl < need && need <= incl) {
            unsigned want = need - excl;
            for (int n = lo; n < hi; ++n) {
                if (__float_as_uint(s_val[n]) == pref) {
                    if (--want == 0u) { s_sel[0] = (unsigned)n; break; }
                }
            }
        }
        __syncthreads();
    }
    if (tid == 0) { cK[bm] = __uint_as_float(pref); nK[bm] = (int)s_sel[0]; }
}

// ---------- kernel 3: per-(b,n) row; reads stored cost column (use_t) ----------
__global__ __launch_bounds__(256) void k_assign(
    const float* __restrict__ pred_bboxes,
    const float* __restrict__ pred_scores,
    const float* __restrict__ tsc,           // cost matrix after k_select (use_t)
    const float* __restrict__ priors,
    const int*   __restrict__ gt_labels,
    const float* __restrict__ gt_bboxes,
    const float* __restrict__ pad,
    const unsigned char* __restrict__ valid,
    const float* __restrict__ cK,
    const int*   __restrict__ nK,
    float* __restrict__ out,
    int use_t)
{
    __shared__ float s_box[M][4];
    __shared__ float s_gc[M][2];
    __shared__ float s_ck[M];
    __shared__ int   s_lab[M];
    __shared__ int   s_nk[M];
    __shared__ unsigned char s_gtv[M];

    const int i = blockIdx.x;
    const int cidx = (i & 7) * 132 + (i >> 3);
    const int b = cidx / 33;
    const int chunk = cidx % 33;
    const int n = chunk * 256 + threadIdx.x;

    if (threadIdx.x < M) {
        int m = threadIdx.x, gi = b * M + m;
        float4 g = ((const float4*)gt_bboxes)[gi];
        s_box[m][0] = g.x; s_box[m][1] = g.y; s_box[m][2] = g.z; s_box[m][3] = g.w;
        s_gc[m][0] = (g.x + g.z) * 0.5f;
        s_gc[m][1] = (g.y + g.w) * 0.5f;
        s_ck[m] = cK[gi];
        s_lab[m] = gt_labels[gi];
        s_nk[m] = nK[gi];
        s_gtv[m] = (pad[gi] > 0.0f) ? 1 : 0;
    }
    __syncthreads();
    if (n >= N) return;

    const size_t idx = (size_t)b * N + n;

    int count = 0, firstm = -1;
    float minc = INFINITY; int amin = 0;
    float firstiou = 0.0f, aminiou = 0.0f;

    if (use_t) {
        const float* tb = tsc + (size_t)b * M * N;
#pragma unroll 4
        for (int m = 0; m < M; m++) {
            float c = tb[(size_t)m * N + n];
            if (c < minc) { minc = c; amin = m; }
            float ckm = s_ck[m]; int nkm = s_nk[m];
            bool matched = s_gtv[m] && (c < ckm || (c == ckm && n <= nkm));
            if (matched) { count++; if (firstm < 0) firstm = m; }
        }
        int mstar = (count > 1) ? amin : firstm;     // count==0 -> firstm == -1
        float mi = 0.0f;
        if (mstar >= 0) {
            float4 p = ((const float4*)pred_bboxes)[idx];
            mi = iou_fn(p.x, p.y, p.z, p.w,
                        s_box[mstar][0], s_box[mstar][1], s_box[mstar][2], s_box[mstar][3]);
        }
        float* o_lab = out;
        float* o_w   = out + (size_t)B * N;
        float* o_box = out + (size_t)2 * B * N;
        float* o_met = out + (size_t)6 * B * N;
        o_w[idx] = 1.0f;
        if (mstar >= 0) {
            o_lab[idx] = (float)s_lab[mstar];
            o_box[idx * 4 + 0] = s_box[mstar][0];
            o_box[idx * 4 + 1] = s_box[mstar][1];
            o_box[idx * 4 + 2] = s_box[mstar][2];
            o_box[idx * 4 + 3] = s_box[mstar][3];
            o_met[idx] = mi;
        } else {
            o_lab[idx] = (float)C;
            o_box[idx * 4 + 0] = 0.0f;
            o_box[idx * 4 + 1] = 0.0f;
            o_box[idx * 4 + 2] = 0.0f;
            o_box[idx * 4 + 3] = 0.0f;
            o_met[idx] = 0.0f;
        }
        return;
    }

    // -------- fallback (use_t == 0): compute costs directly --------
    const float4 p = ((const float4*)pred_bboxes)[idx];
    const float4 pr = ((const float4*)priors)[n];
    const int vn = valid[idx];
    const float* scores = pred_scores + idx * C;

    for (int m = 0; m < M; m++) {
        float iou = iou_fn(p.x, p.y, p.z, p.w,
                           s_box[m][0], s_box[m][1], s_box[m][2], s_box[m][3]);
        float c;
        if (vn) {
            float logit = scores[s_lab[m]];
            c = cost_fn(iou, logit, pr.x, pr.y, pr.z, s_gc[m][0], s_gc[m][1]);
        } else {
            c = INF_COST;
        }
        if (c < minc) { minc = c; amin = m; aminiou = iou; }
        float ckm = s_ck[m]; int nkm = s_nk[m];
        bool matched = s_gtv[m] && (c < ckm || (c == ckm && n <= nkm));
        if (matched) { count++; if (firstm < 0) { firstm = m; firstiou = iou; } }
    }

    int mstar; float mi;
    if (count > 1)       { mstar = amin;   mi = aminiou; }
    else if (count == 1) { mstar = firstm; mi = firstiou; }
    else                 { mstar = -1;     mi = 0.0f; }

    float* o_lab = out;
    float* o_w   = out + (size_t)B * N;
    float* o_box = out + (size_t)2 * B * N;
    float* o_met = out + (size_t)6 * B * N;
    o_w[idx] = 1.0f;
    if (mstar >= 0) {
        o_lab[idx] = (float)s_lab[mstar];
        o_box[idx * 4 + 0] = s_box[mstar][0];
        o_box[idx * 4 + 1] = s_box[mstar][1];
        o_box[idx * 4 + 2] = s_box[mstar][2];
        o_box[idx * 4 + 3] = s_box[mstar][3];
        o_met[idx] = mi;
    } else {
        o_lab[idx] = (float)C;
        o_box[idx * 4 + 0] = 0.0f;
        o_box[idx * 4 + 1] = 0.0f;
        o_box[idx * 4 + 2] = 0.0f;
        o_box[idx * 4 + 3] = 0.0f;
        o_met[idx] = 0.0f;
    }
}

extern "C" void kernel_launch(void* const* d_in, const int* in_sizes, int n_in,
                              void* d_out, int out_size, void* d_ws, size_t ws_size,
                              hipStream_t stream) {
    const float* pred_bboxes = (const float*)d_in[0];
    const float* pred_scores = (const float*)d_in[1];
    const float* priors      = (const float*)d_in[2];
    const int*   gt_labels   = (const int*)d_in[3];
    const float* gt_bboxes   = (const float*)d_in[4];
    const float* pad         = (const float*)d_in[5];
    float* out = (float*)d_out;

    const size_t t_bytes = (size_t)B * M * N * sizeof(float);
    const size_t need = t_bytes + (size_t)B * N + (size_t)B * M * 8;
    const int use_t = (ws_size >= need) ? 1 : 0;

    unsigned char* ws = (unsigned char*)d_ws;
    float* tsc; unsigned char* valid; float* cKp; int* nKp;
    if (use_t) {
        tsc   = (float*)ws;
        valid = ws + t_bytes;
        cKp   = (float*)(ws + t_bytes + (size_t)B * N);
        nKp   = (int*)  (ws + t_bytes + (size_t)B * N + (size_t)B * M * 4);
    } else {
        tsc   = (float*)ws;   // never dereferenced
        valid = ws;
        cKp   = (float*)(ws + (size_t)B * N);
        nKp   = (int*)  (ws + (size_t)B * N + (size_t)B * M * 4);
    }

    k_valid<<<(B * N + 255) / 256, 256, 0, stream>>>(priors, gt_bboxes, pad, valid);
    if (use_t)
        k_transpose<<<B * 132, 256, 0, stream>>>(pred_scores, gt_labels, tsc);
    k_select<<<B * M, 256, 0, stream>>>(pred_bboxes, pred_scores, tsc, priors, gt_labels,
                                        gt_bboxes, pad, valid, cKp, nKp, use_t);
    k_assign<<<33 * B, 256, 0, stream>>>(pred_bboxes, pred_scores, tsc, priors, gt_labels,
                                         gt_bboxes, pad, valid, cKp, nKp, out, use_t);
}